// Round 2
// baseline (816.059 us; speedup 1.0000x reference)
//
#include <hip/hip_runtime.h>
#include <math.h>
#include <stdint.h>

// PaiNN QM encoder, refactored:
//   U = V_JK @ W1b  (N,3,256)   T = b1 + n_i@W1c + S_JK@W1d  (N,256)
//   per edge: m1 = T[i] + e_pi@W1a + r_hat . U[i] -> silu -> @W2 -> silu -> @w3 -> *cw -> scatter
// Round 2: CSR-bin edges by atom so U/T are loaded once per atom (kills the
// 512 MB random gather); bf16 xT tile in LDS; __sinf + coalesced EPI in kB0.

#define L_DIM 6
#define F_DIM 256
#define FH_DIM 128
#define DRBF 32
#define CUTOFF_F 4.0f
#define PI_F 3.14159265358979323846f

__device__ __forceinline__ float silu_f(float x){ return x / (1.f + __expf(-x)); }

__device__ __forceinline__ unsigned short f2bf(float f){
    uint32_t u = __float_as_uint(f);
    uint32_t r = (u + 0x7fffu + ((u >> 16) & 1u)) >> 16;   // RNE
    return (unsigned short)r;
}

// ---------------- Kernel A1: attention + S_JK / V_JK / n_i ----------------
__global__ __launch_bounds__(256) void kA1(
    const float* __restrict__ s_stack, const float* __restrict__ v_stack,
    const float* __restrict__ attn_w1, const float* __restrict__ attn_b1,
    const float* __restrict__ attn_w2, const float* __restrict__ attn_b2,
    float* __restrict__ VJK, float* __restrict__ SJK, float* __restrict__ NI,
    int N)
{
    __shared__ float red[4][8][3];
    __shared__ float alds[8][L_DIM];

    const int t = threadIdx.x;
    const int n0 = blockIdx.x * 8;
    const int j = t & (FH_DIM - 1);
    const int lgu  = __builtin_amdgcn_readfirstlane(t >> 7);
    const int wave = __builtin_amdgcn_readfirstlane(t >> 6);

    const float* sb[8];
    #pragma unroll
    for (int a = 0; a < 8; a++){
        int n = n0 + a; if (n > N-1) n = N-1;
        sb[a] = s_stack + ((size_t)n * L_DIM + (size_t)lgu * 3) * F_DIM;
    }

    float hacc[8][3];
    #pragma unroll
    for (int a = 0; a < 8; a++){ hacc[a][0]=0.f; hacc[a][1]=0.f; hacc[a][2]=0.f; }

    #pragma unroll 4
    for (int f = 0; f < F_DIM; f++){
        float w = attn_w1[f * FH_DIM + j];
        #pragma unroll
        for (int a = 0; a < 8; a++){
            hacc[a][0] = fmaf(sb[a][f],           w, hacc[a][0]);
            hacc[a][1] = fmaf(sb[a][F_DIM + f],   w, hacc[a][1]);
            hacc[a][2] = fmaf(sb[a][2*F_DIM + f], w, hacc[a][2]);
        }
    }

    const float b1j = attn_b1[j];
    const float w2j = attn_w2[j];
    const float b2s = attn_b2[0];

    #pragma unroll
    for (int a = 0; a < 8; a++){
        #pragma unroll
        for (int l3 = 0; l3 < 3; l3++){
            float pre = hacc[a][l3] + b1j;
            float p = silu_f(pre) * w2j;
            #pragma unroll
            for (int m = 32; m >= 1; m >>= 1) p += __shfl_xor(p, m, 64);
            if ((t & 63) == 0) red[wave][a][l3] = p;
        }
    }
    __syncthreads();
    if (t < 48){
        int a = t / L_DIM, l = t % L_DIM;
        int lg2 = l / 3, l3 = l % 3;
        alds[a][l] = red[lg2*2][a][l3] + red[lg2*2+1][a][l3] + b2s;
    }
    __syncthreads();
    if (t < 8){
        float mx = -1e30f;
        #pragma unroll
        for (int l = 0; l < L_DIM; l++) mx = fmaxf(mx, alds[t][l]);
        float e[L_DIM]; float s = 0.f;
        #pragma unroll
        for (int l = 0; l < L_DIM; l++){ e[l] = __expf(alds[t][l] - mx); s += e[l]; }
        float inv = 1.f / s;
        #pragma unroll
        for (int l = 0; l < L_DIM; l++) alds[t][l] = e[l] * inv;
    }
    __syncthreads();

    const int f = t;
    for (int a = 0; a < 8; a++){
        int n = n0 + a; if (n >= N) break;
        float aw[L_DIM];
        #pragma unroll
        for (int l = 0; l < L_DIM; l++) aw[l] = alds[a][l];
        const float* sp = s_stack + (size_t)n * L_DIM * F_DIM + f;
        float sjk = 0.f;
        #pragma unroll
        for (int l = 0; l < L_DIM; l++) sjk = fmaf(aw[l], sp[l * F_DIM], sjk);
        const float* vp = v_stack + (size_t)n * L_DIM * 3 * F_DIM + f;
        float v0 = 0.f, v1 = 0.f, v2 = 0.f;
        #pragma unroll
        for (int l = 0; l < L_DIM; l++){
            v0 = fmaf(aw[l], vp[(l*3+0)*F_DIM], v0);
            v1 = fmaf(aw[l], vp[(l*3+1)*F_DIM], v1);
            v2 = fmaf(aw[l], vp[(l*3+2)*F_DIM], v2);
        }
        SJK[(size_t)n * F_DIM + f] = sjk;
        VJK[((size_t)n*3 + 0) * F_DIM + f] = v0;
        VJK[((size_t)n*3 + 1) * F_DIM + f] = v1;
        VJK[((size_t)n*3 + 2) * F_DIM + f] = v2;
        NI[(size_t)n * F_DIM + f] = sqrtf(v0*v0 + v1*v1 + v2*v2);
    }
}

// ---------------- Kernel A2: U = VJK@W1b, T = b1 + NI@W1c + SJK@W1d ----------------
__global__ __launch_bounds__(256) void kA2(
    const float* __restrict__ msg_w1, const float* __restrict__ msg_b1,
    const float* __restrict__ VJK, const float* __restrict__ SJK, const float* __restrict__ NI,
    float* __restrict__ U, float* __restrict__ T, int N)
{
    const int t = threadIdx.x;
    const int n0 = blockIdx.x * 8;

    float uacc[8][3];
    #pragma unroll
    for (int a = 0; a < 8; a++){ uacc[a][0]=0.f; uacc[a][1]=0.f; uacc[a][2]=0.f; }

    #pragma unroll 2
    for (int f = 0; f < F_DIM; f++){
        float w = msg_w1[(size_t)(DRBF + f) * F_DIM + t];
        #pragma unroll
        for (int a = 0; a < 8; a++){
            int n = n0 + a; if (n > N-1) n = N-1;
            const float* vb = VJK + (size_t)n * 3 * F_DIM + f;
            uacc[a][0] = fmaf(vb[0],       w, uacc[a][0]);
            uacc[a][1] = fmaf(vb[F_DIM],   w, uacc[a][1]);
            uacc[a][2] = fmaf(vb[2*F_DIM], w, uacc[a][2]);
        }
    }
    #pragma unroll
    for (int a = 0; a < 8; a++){
        int n = n0 + a;
        if (n < N){
            U[((size_t)n*3 + 0)*F_DIM + t] = uacc[a][0];
            U[((size_t)n*3 + 1)*F_DIM + t] = uacc[a][1];
            U[((size_t)n*3 + 2)*F_DIM + t] = uacc[a][2];
        }
    }

    float tacc[8];
    const float b = msg_b1[t];
    #pragma unroll
    for (int a = 0; a < 8; a++) tacc[a] = b;

    #pragma unroll 2
    for (int f = 0; f < F_DIM; f++){
        float wc = msg_w1[(size_t)(DRBF + F_DIM   + f) * F_DIM + t];
        float wd = msg_w1[(size_t)(DRBF + 2*F_DIM + f) * F_DIM + t];
        #pragma unroll
        for (int a = 0; a < 8; a++){
            int n = n0 + a; if (n > N-1) n = N-1;
            tacc[a] = fmaf(NI [(size_t)n*F_DIM + f], wc, tacc[a]);
            tacc[a] = fmaf(SJK[(size_t)n*F_DIM + f], wd, tacc[a]);
        }
    }
    #pragma unroll
    for (int a = 0; a < 8; a++){
        int n = n0 + a;
        if (n < N) T[(size_t)n*F_DIM + t] = tacc[a];
    }
}

// ---------------- Kernel B0: per-edge geometry -> EPI (E,32), RCW (E,4) ----------------
// __sinf (native) + LDS transpose so EPI stores are coalesced.
__global__ __launch_bounds__(256) void kB0(
    const int* __restrict__ pe, const float* __restrict__ disp,
    const float* __restrict__ cell,
    const float* __restrict__ atom_xyz, const float* __restrict__ probe_xyz,
    float* __restrict__ EPI, float* __restrict__ RCW, int E)
{
    __shared__ float sl[DRBF][257];

    const int t = threadIdx.x;
    const int e0 = blockIdx.x * 256;
    const int e  = min(e0 + t, E - 1);

    int i = pe[(size_t)e*2];
    int p = pe[(size_t)e*2 + 1];
    float d0 = disp[(size_t)e*3], d1 = disp[(size_t)e*3+1], d2 = disp[(size_t)e*3+2];
    float sx = d0*cell[0] + d1*cell[3] + d2*cell[6];
    float sy = d0*cell[1] + d1*cell[4] + d2*cell[7];
    float sz = d0*cell[2] + d1*cell[5] + d2*cell[8];
    float dx = probe_xyz[(size_t)p*3+0] - (atom_xyz[(size_t)i*3+0] + sx);
    float dy = probe_xyz[(size_t)p*3+1] - (atom_xyz[(size_t)i*3+1] + sy);
    float dz = probe_xyz[(size_t)p*3+2] - (atom_xyz[(size_t)i*3+2] + sz);
    float dist = sqrtf(dx*dx + dy*dy + dz*dz);
    float inv = 1.f / (dist + 1e-8f);
    if (e0 + t < E){
        float4 rc;
        rc.x = dx * inv; rc.y = dy * inv; rc.z = dz * inv;
        rc.w = (dist < CUTOFF_F) ? 0.5f * (__cosf(PI_F * dist / CUTOFF_F) + 1.f) : 0.f;
        *(float4*)&RCW[(size_t)(e0 + t)*4] = rc;
    }
    float base = dist * (PI_F / CUTOFF_F);
    #pragma unroll
    for (int k = 0; k < DRBF; k++)
        sl[k][t] = __sinf(base * (float)(k+1)) * inv;
    __syncthreads();
    // write out transposed: EPI[(e0+r)*32 + c] = sl[c][r], coalesced 1 KB stores
    #pragma unroll 4
    for (int chunk = 0; chunk < 32; chunk++){
        int flat = chunk * 256 + t;
        int r = flat >> 5, c = flat & 31;
        if (e0 + r < E)
            EPI[(size_t)(e0 + r) * DRBF + c] = sl[c][r];
    }
}

// ---------------- CSR binning: hist, scan, scatter ----------------
__global__ __launch_bounds__(256) void kHist(const int* __restrict__ pe, int* __restrict__ cnt, int E){
    int e = blockIdx.x * 256 + threadIdx.x;
    if (e < E) atomicAdd(&cnt[pe[(size_t)e*2]], 1);
}

__global__ __launch_bounds__(1024) void kScan(const int* __restrict__ cnt, int* __restrict__ off, int N){
    __shared__ int sums[1024];
    const int t = threadIdx.x;
    const int base = t * 8;
    int c[8]; int s = 0;
    #pragma unroll
    for (int j = 0; j < 8; j++){
        int v = (base + j < N) ? cnt[base + j] : 0;
        c[j] = s; s += v;
    }
    sums[t] = s;
    __syncthreads();
    for (int d = 1; d < 1024; d <<= 1){
        int v = (t >= d) ? sums[t - d] : 0;
        __syncthreads();
        sums[t] += v;
        __syncthreads();
    }
    int excl = (t == 0) ? 0 : sums[t - 1];
    #pragma unroll
    for (int j = 0; j < 8; j++)
        if (base + j < N) off[base + j] = excl + c[j];
    if (t == 1023) off[N] = sums[1023];
}

__global__ __launch_bounds__(256) void kScatter(const int* __restrict__ pe,
    const int* __restrict__ off, int* __restrict__ pos, int* __restrict__ perm, int E){
    int e = blockIdx.x * 256 + threadIdx.x;
    if (e < E){
        int i = pe[(size_t)e*2];
        int slot = atomicAdd(&pos[i], 1);
        perm[off[i] + slot] = e;
    }
}

// ---------------- Kernel B1: per-atom fused edge MLP + scatter ----------------
// Block owns 8 atoms; U/T loaded once per atom into registers. Edges accumulate
// into a 32-wide bf16 x-tile in LDS; layer2 (256->128) + layer3 per batch.
__global__ __launch_bounds__(256) void kB1(
    const int* __restrict__ pe,
    const float* __restrict__ EPI, const float* __restrict__ RCW,
    const float* __restrict__ U, const float* __restrict__ T,
    const float* __restrict__ msg_w1,
    const float* __restrict__ msg_w2, const float* __restrict__ msg_b2,
    const float* __restrict__ msg_w3, const float* __restrict__ msg_b3,
    const int* __restrict__ off, const int* __restrict__ perm,
    float* __restrict__ rho, int N, int E)
{
    __shared__ unsigned short xTb[F_DIM][34];   // bf16 x, [k][edge-slot]
    __shared__ float cw_l[32];
    __shared__ int   pp_l[32];

    const int t = threadIdx.x;
    const int a0 = blockIdx.x * 8;

    float w1a[DRBF];
    #pragma unroll
    for (int k = 0; k < DRBF; k++) w1a[k] = msg_w1[(size_t)k * F_DIM + t];

    const int hg = t & 15;
    const int e2 = (t >> 4) * 2;
    const int h0 = hg * 8;
    float w3r[8], b2r[8];
    #pragma unroll
    for (int hh = 0; hh < 8; hh++){ w3r[hh] = msg_w3[h0+hh]; b2r[hh] = msg_b2[h0+hh]; }
    const float b3 = msg_b3[0];

    auto do_l2 = [&](int valid){
        __syncthreads();
        float acc2[2][8];
        #pragma unroll
        for (int hh = 0; hh < 8; hh++){ acc2[0][hh] = b2r[hh]; acc2[1][hh] = b2r[hh]; }
        #pragma unroll 4
        for (int k = 0; k < F_DIM; k++){
            uint32_t u = *(const uint32_t*)&xTb[k][e2];
            float x0 = __uint_as_float(u << 16);
            float x1 = __uint_as_float(u & 0xffff0000u);
            const float4* wr = (const float4*)(msg_w2 + (size_t)k * FH_DIM + h0);
            float4 wa = wr[0], wb = wr[1];
            float wv[8] = {wa.x, wa.y, wa.z, wa.w, wb.x, wb.y, wb.z, wb.w};
            #pragma unroll
            for (int hh = 0; hh < 8; hh++){
                acc2[0][hh] = fmaf(x0, wv[hh], acc2[0][hh]);
                acc2[1][hh] = fmaf(x1, wv[hh], acc2[1][hh]);
            }
        }
        #pragma unroll
        for (int ei = 0; ei < 2; ei++){
            float msum = 0.f;
            #pragma unroll
            for (int hh = 0; hh < 8; hh++)
                msum = fmaf(silu_f(acc2[ei][hh]), w3r[hh], msum);
            #pragma unroll
            for (int m = 8; m >= 1; m >>= 1) msum += __shfl_xor(msum, m, 64);
            if (hg == 0 && (e2 + ei) < valid)
                atomicAdd(&rho[pp_l[e2 + ei]], (msum + b3) * cw_l[e2 + ei]);
        }
        __syncthreads();
    };

    int nbuf = 0;
    for (int a = 0; a < 8; a++){
        const int atom = a0 + a;
        if (atom >= N) break;
        const float Tt = T[(size_t)atom * F_DIM + t];
        const float* Up = U + (size_t)atom * 3 * F_DIM;
        const float u0 = Up[t], u1 = Up[F_DIM + t], u2 = Up[2*F_DIM + t];
        const int beg = off[atom], end = off[atom + 1];
        for (int s2 = beg; s2 < end; s2++){
            const int eec = perm[s2];                        // uniform
            const float* rc = RCW + (size_t)eec * 4;
            const float rx = rc[0], ry = rc[1], rz = rc[2], cwv = rc[3];
            const float* ep = EPI + (size_t)eec * DRBF;      // uniform -> s_loads
            float p0 = 0.f, p1 = 0.f, p2 = 0.f, p3 = 0.f;
            #pragma unroll
            for (int k = 0; k < DRBF; k += 4){
                p0 = fmaf(ep[k+0], w1a[k+0], p0);
                p1 = fmaf(ep[k+1], w1a[k+1], p1);
                p2 = fmaf(ep[k+2], w1a[k+2], p2);
                p3 = fmaf(ep[k+3], w1a[k+3], p3);
            }
            float acc = Tt + (p0 + p1) + (p2 + p3);
            acc = fmaf(rx, u0, fmaf(ry, u1, fmaf(rz, u2, acc)));
            xTb[t][nbuf] = f2bf(silu_f(acc));
            if (t == 0){ cw_l[nbuf] = cwv; pp_l[nbuf] = pe[(size_t)eec*2 + 1]; }
            nbuf++;
            if (nbuf == 32){ do_l2(32); nbuf = 0; }
        }
    }
    if (nbuf > 0) do_l2(nbuf);
}

extern "C" void kernel_launch(void* const* d_in, const int* in_sizes, int n_in,
                              void* d_out, int out_size, void* d_ws, size_t ws_size,
                              hipStream_t stream)
{
    const float* s_stack   = (const float*)d_in[0];
    const float* v_stack   = (const float*)d_in[1];
    const float* atom_xyz  = (const float*)d_in[2];
    const float* probe_xyz = (const float*)d_in[3];
    const float* cell      = (const float*)d_in[4];
    const float* disp      = (const float*)d_in[5];
    const float* attn_w1   = (const float*)d_in[6];
    const float* attn_b1   = (const float*)d_in[7];
    const float* attn_w2   = (const float*)d_in[8];
    const float* attn_b2   = (const float*)d_in[9];
    const float* msg_w1    = (const float*)d_in[10];
    const float* msg_b1    = (const float*)d_in[11];
    const float* msg_w2    = (const float*)d_in[12];
    const float* msg_b2    = (const float*)d_in[13];
    const float* msg_w3    = (const float*)d_in[14];
    const float* msg_b3    = (const float*)d_in[15];
    const int*   pe        = (const int*)d_in[16];

    const int N = in_sizes[0] / (L_DIM * F_DIM);
    const int E = in_sizes[16] / 2;
    const int P = out_size;
    const size_t NF = (size_t)N * F_DIM;

    float* ws = (float*)d_ws;
    // region 1 (5*NF floats): VJK|SJK|NI for phase A; then EPI|RCW|CSR for phase B
    float* VJK = ws;
    float* SJK = ws + 3*NF;
    float* NI  = ws + 4*NF;
    float* EPI = ws;                           // [0, E*32)
    float* RCW = ws + (size_t)E * DRBF;        // [E*32, E*36)
    int*   cnt  = (int*)(ws + (size_t)E * 36); // CSR block inside region 1
    int*   pos  = cnt + N;
    int*   offs = pos + N;
    int*   perm = offs + N + 1;
    // region 2: U | T
    float* Ubuf = ws + 5*NF;
    float* Tbuf = ws + 8*NF;

    hipMemsetAsync(d_out, 0, (size_t)P * sizeof(float), stream);

    const int gA = (N + 7) / 8;
    kA1<<<gA, 256, 0, stream>>>(s_stack, v_stack, attn_w1, attn_b1, attn_w2, attn_b2,
                                VJK, SJK, NI, N);
    kA2<<<gA, 256, 0, stream>>>(msg_w1, msg_b1, VJK, SJK, NI, Ubuf, Tbuf, N);

    // region 1 is dead now; reuse for EPI/RCW/CSR
    hipMemsetAsync(cnt, 0, 2 * (size_t)N * sizeof(int), stream);

    const int gE = (E + 255) / 256;
    kB0<<<gE, 256, 0, stream>>>(pe, disp, cell, atom_xyz, probe_xyz, EPI, RCW, E);
    kHist<<<gE, 256, 0, stream>>>(pe, cnt, E);
    kScan<<<1, 1024, 0, stream>>>(cnt, offs, N);
    kScatter<<<gE, 256, 0, stream>>>(pe, offs, pos, perm, E);

    kB1<<<(N + 7) / 8, 256, 0, stream>>>(pe, EPI, RCW, Ubuf, Tbuf, msg_w1,
                                         msg_w2, msg_b2, msg_w3, msg_b3,
                                         offs, perm, (float*)d_out, N, E);
}

// Round 3
// 522.101 us; speedup vs baseline: 1.5630x; 1.5630x over previous
//
#include <hip/hip_runtime.h>
#include <math.h>
#include <stdint.h>

// PaiNN QM encoder, round 3.
//   U = V_JK @ W1b  (N,3,256)   T = b1 + n_i@W1c + S_JK@W1d  (N,256)
//   per edge: x = silu(T[i] + e_pi@W1a + r_hat.U[i]); m = (silu(x@W2+b2))@w3+b3
// kB1: static 32-edge batches over CSR-sorted perm; layer-2 via bf16 MFMA with
// W2^T bf16 fragments cached in registers. kA1/kA2: vector-load register-tiled
// GEMMs (no scalar-load chains).

#define L_DIM 6
#define F_DIM 256
#define FH_DIM 128
#define DRBF 32
#define CUTOFF_F 4.0f
#define PI_F 3.14159265358979323846f

using bf16x8 = __attribute__((ext_vector_type(8))) short;
using f32x4v = __attribute__((ext_vector_type(4))) float;

__device__ __forceinline__ float silu_f(float x){ return x / (1.f + __expf(-x)); }

__device__ __forceinline__ unsigned short f2bf(float f){
    uint32_t u = __float_as_uint(f);
    uint32_t r = (u + 0x7fffu + ((u >> 16) & 1u)) >> 16;   // RNE
    return (unsigned short)r;
}

// ---------------- Kernel A1: attention + S_JK / V_JK / n_i ----------------
// thread t: atom a = t>>5 (8/block), cols j = (t&31)*4..+4 of FH=128.
__global__ __launch_bounds__(256) void kA1(
    const float* __restrict__ s_stack, const float* __restrict__ v_stack,
    const float* __restrict__ attn_w1, const float* __restrict__ attn_b1,
    const float* __restrict__ attn_w2,
    float* __restrict__ VJK, float* __restrict__ SJK, float* __restrict__ NI,
    int N)
{
    __shared__ float llds[8][L_DIM];

    const int t  = threadIdx.x;
    const int a  = t >> 5;
    const int jg = t & 31;
    const int n0 = blockIdx.x * 8;
    const int n  = min(n0 + a, N - 1);

    const float* sp = s_stack + (size_t)n * (L_DIM * F_DIM);

    float hacc[L_DIM][4];
    #pragma unroll
    for (int l = 0; l < L_DIM; l++)
        #pragma unroll
        for (int jj = 0; jj < 4; jj++) hacc[l][jj] = 0.f;

    #pragma unroll 4
    for (int f = 0; f < F_DIM; f++){
        float4 w = *(const float4*)&attn_w1[(size_t)f * FH_DIM + jg*4];
        float w8[4] = {w.x, w.y, w.z, w.w};
        #pragma unroll
        for (int l = 0; l < L_DIM; l++){
            float sv = sp[l * F_DIM + f];        // same addr across 32-lane group
            #pragma unroll
            for (int jj = 0; jj < 4; jj++) hacc[l][jj] = fmaf(sv, w8[jj], hacc[l][jj]);
        }
    }

    float4 b1v = *(const float4*)&attn_b1[jg*4];
    float4 w2v = *(const float4*)&attn_w2[jg*4];
    float b1a[4] = {b1v.x, b1v.y, b1v.z, b1v.w};
    float w2a[4] = {w2v.x, w2v.y, w2v.z, w2v.w};

    #pragma unroll
    for (int l = 0; l < L_DIM; l++){
        float s = 0.f;
        #pragma unroll
        for (int jj = 0; jj < 4; jj++)
            s = fmaf(silu_f(hacc[l][jj] + b1a[jj]), w2a[jj], s);
        #pragma unroll
        for (int m = 16; m >= 1; m >>= 1) s += __shfl_xor(s, m, 64);
        if (jg == 0) llds[a][l] = s;            // attn_b2 dropped: softmax-invariant
    }
    __syncthreads();
    if (t < 8){
        float mx = -1e30f;
        #pragma unroll
        for (int l = 0; l < L_DIM; l++) mx = fmaxf(mx, llds[t][l]);
        float e[L_DIM]; float s = 0.f;
        #pragma unroll
        for (int l = 0; l < L_DIM; l++){ e[l] = __expf(llds[t][l] - mx); s += e[l]; }
        float inv = 1.f / s;
        #pragma unroll
        for (int l = 0; l < L_DIM; l++) llds[t][l] = e[l] * inv;
    }
    __syncthreads();

    // weighted sums: thread t owns feature f=t
    const int f = t;
    for (int aa = 0; aa < 8; aa++){
        int nn = n0 + aa; if (nn >= N) break;
        float aw[L_DIM];
        #pragma unroll
        for (int l = 0; l < L_DIM; l++) aw[l] = llds[aa][l];
        const float* sp2 = s_stack + (size_t)nn * L_DIM * F_DIM + f;
        float sjk = 0.f;
        #pragma unroll
        for (int l = 0; l < L_DIM; l++) sjk = fmaf(aw[l], sp2[l * F_DIM], sjk);
        const float* vp = v_stack + (size_t)nn * L_DIM * 3 * F_DIM + f;
        float v0 = 0.f, v1 = 0.f, v2 = 0.f;
        #pragma unroll
        for (int l = 0; l < L_DIM; l++){
            v0 = fmaf(aw[l], vp[(l*3+0)*F_DIM], v0);
            v1 = fmaf(aw[l], vp[(l*3+1)*F_DIM], v1);
            v2 = fmaf(aw[l], vp[(l*3+2)*F_DIM], v2);
        }
        SJK[(size_t)nn * F_DIM + f] = sjk;
        VJK[((size_t)nn*3 + 0) * F_DIM + f] = v0;
        VJK[((size_t)nn*3 + 1) * F_DIM + f] = v1;
        VJK[((size_t)nn*3 + 2) * F_DIM + f] = v2;
        NI[(size_t)nn * F_DIM + f] = sqrtf(v0*v0 + v1*v1 + v2*v2);
    }
}

// ---------------- Kernel A2: U = VJK@W1b, T = b1 + NI@W1c + SJK@W1d ----------------
// thread t: atom a = t>>5 (8/block), cols j = (t&31)*8..+8.
__global__ __launch_bounds__(256) void kA2(
    const float* __restrict__ msg_w1, const float* __restrict__ msg_b1,
    const float* __restrict__ VJK, const float* __restrict__ SJK, const float* __restrict__ NI,
    float* __restrict__ U, float* __restrict__ T, int N)
{
    const int t  = threadIdx.x;
    const int a  = t >> 5;
    const int jg = t & 31;
    const int n  = min(blockIdx.x * 8 + a, N - 1);

    const float* vrow = VJK + (size_t)n * (3 * F_DIM);
    const float* nrow = NI  + (size_t)n * F_DIM;
    const float* srow = SJK + (size_t)n * F_DIM;

    float uacc[3][8];
    #pragma unroll
    for (int c = 0; c < 3; c++)
        #pragma unroll
        for (int jj = 0; jj < 8; jj++) uacc[c][jj] = 0.f;

    #pragma unroll 2
    for (int k = 0; k < F_DIM; k++){
        const float* wrow = msg_w1 + (size_t)(DRBF + k) * F_DIM + jg*8;
        float4 wa = *(const float4*)wrow;
        float4 wb = *(const float4*)(wrow + 4);
        float w8[8] = {wa.x, wa.y, wa.z, wa.w, wb.x, wb.y, wb.z, wb.w};
        float v0 = vrow[k], v1 = vrow[F_DIM + k], v2 = vrow[2*F_DIM + k];
        #pragma unroll
        for (int jj = 0; jj < 8; jj++){
            uacc[0][jj] = fmaf(v0, w8[jj], uacc[0][jj]);
            uacc[1][jj] = fmaf(v1, w8[jj], uacc[1][jj]);
            uacc[2][jj] = fmaf(v2, w8[jj], uacc[2][jj]);
        }
    }
    #pragma unroll
    for (int c = 0; c < 3; c++){
        float4 o0 = {uacc[c][0], uacc[c][1], uacc[c][2], uacc[c][3]};
        float4 o1 = {uacc[c][4], uacc[c][5], uacc[c][6], uacc[c][7]};
        *(float4*)&U[((size_t)n*3 + c)*F_DIM + jg*8]     = o0;
        *(float4*)&U[((size_t)n*3 + c)*F_DIM + jg*8 + 4] = o1;
    }

    float tacc[8];
    {
        float4 ba = *(const float4*)&msg_b1[jg*8];
        float4 bb = *(const float4*)&msg_b1[jg*8 + 4];
        tacc[0]=ba.x; tacc[1]=ba.y; tacc[2]=ba.z; tacc[3]=ba.w;
        tacc[4]=bb.x; tacc[5]=bb.y; tacc[6]=bb.z; tacc[7]=bb.w;
    }
    #pragma unroll 2
    for (int k = 0; k < F_DIM; k++){
        const float* wc = msg_w1 + (size_t)(DRBF + F_DIM   + k) * F_DIM + jg*8;
        const float* wd = msg_w1 + (size_t)(DRBF + 2*F_DIM + k) * F_DIM + jg*8;
        float4 ca = *(const float4*)wc; float4 cb = *(const float4*)(wc + 4);
        float4 da = *(const float4*)wd; float4 db = *(const float4*)(wd + 4);
        float c8[8] = {ca.x, ca.y, ca.z, ca.w, cb.x, cb.y, cb.z, cb.w};
        float d8[8] = {da.x, da.y, da.z, da.w, db.x, db.y, db.z, db.w};
        float ni = nrow[k], sj = srow[k];
        #pragma unroll
        for (int jj = 0; jj < 8; jj++){
            tacc[jj] = fmaf(ni, c8[jj], tacc[jj]);
            tacc[jj] = fmaf(sj, d8[jj], tacc[jj]);
        }
    }
    {
        float4 o0 = {tacc[0], tacc[1], tacc[2], tacc[3]};
        float4 o1 = {tacc[4], tacc[5], tacc[6], tacc[7]};
        *(float4*)&T[(size_t)n*F_DIM + jg*8]     = o0;
        *(float4*)&T[(size_t)n*F_DIM + jg*8 + 4] = o1;
    }
}

// ---------------- kPrep: W2 (256x128 f32) -> W2t bf16 (128 x 256) ----------------
__global__ __launch_bounds__(256) void kPrep(
    const float* __restrict__ msg_w2, unsigned short* __restrict__ w2t)
{
    const int h = blockIdx.x;      // 0..127
    const int k = threadIdx.x;     // 0..255
    w2t[(size_t)h * F_DIM + k] = f2bf(msg_w2[(size_t)k * FH_DIM + h]);
}

// ---------------- Kernel B0: per-edge geometry -> EPI (E,32), RCW (E,4) ----------------
__global__ __launch_bounds__(256) void kB0(
    const int* __restrict__ pe, const float* __restrict__ disp,
    const float* __restrict__ cell,
    const float* __restrict__ atom_xyz, const float* __restrict__ probe_xyz,
    float* __restrict__ EPI, float* __restrict__ RCW, int E)
{
    __shared__ float sl[DRBF][257];

    const int t = threadIdx.x;
    const int e0 = blockIdx.x * 256;
    const int e  = min(e0 + t, E - 1);

    int i = pe[(size_t)e*2];
    int p = pe[(size_t)e*2 + 1];
    float d0 = disp[(size_t)e*3], d1 = disp[(size_t)e*3+1], d2 = disp[(size_t)e*3+2];
    float sx = d0*cell[0] + d1*cell[3] + d2*cell[6];
    float sy = d0*cell[1] + d1*cell[4] + d2*cell[7];
    float sz = d0*cell[2] + d1*cell[5] + d2*cell[8];
    float dx = probe_xyz[(size_t)p*3+0] - (atom_xyz[(size_t)i*3+0] + sx);
    float dy = probe_xyz[(size_t)p*3+1] - (atom_xyz[(size_t)i*3+1] + sy);
    float dz = probe_xyz[(size_t)p*3+2] - (atom_xyz[(size_t)i*3+2] + sz);
    float dist = sqrtf(dx*dx + dy*dy + dz*dz);
    float inv = 1.f / (dist + 1e-8f);
    if (e0 + t < E){
        float4 rc;
        rc.x = dx * inv; rc.y = dy * inv; rc.z = dz * inv;
        rc.w = (dist < CUTOFF_F) ? 0.5f * (__cosf(PI_F * dist / CUTOFF_F) + 1.f) : 0.f;
        *(float4*)&RCW[(size_t)(e0 + t)*4] = rc;
    }
    float base = dist * (PI_F / CUTOFF_F);
    #pragma unroll
    for (int k = 0; k < DRBF; k++)
        sl[k][t] = __sinf(base * (float)(k+1)) * inv;
    __syncthreads();
    #pragma unroll 4
    for (int chunk = 0; chunk < 32; chunk++){
        int flat = chunk * 256 + t;
        int r = flat >> 5, c = flat & 31;
        if (e0 + r < E)
            EPI[(size_t)(e0 + r) * DRBF + c] = sl[c][r];
    }
}

// ---------------- CSR binning ----------------
__global__ __launch_bounds__(256) void kHist(const int* __restrict__ pe, int* __restrict__ cnt, int E){
    int e = blockIdx.x * 256 + threadIdx.x;
    if (e < E) atomicAdd(&cnt[pe[(size_t)e*2]], 1);
}

__global__ __launch_bounds__(1024) void kScan(const int* __restrict__ cnt, int* __restrict__ off, int N){
    __shared__ int sums[1024];
    const int t = threadIdx.x;
    const int base = t * 8;
    int c[8]; int s = 0;
    #pragma unroll
    for (int j = 0; j < 8; j++){
        int v = (base + j < N) ? cnt[base + j] : 0;
        c[j] = s; s += v;
    }
    sums[t] = s;
    __syncthreads();
    for (int d = 1; d < 1024; d <<= 1){
        int v = (t >= d) ? sums[t - d] : 0;
        __syncthreads();
        sums[t] += v;
        __syncthreads();
    }
    int excl = (t == 0) ? 0 : sums[t - 1];
    #pragma unroll
    for (int j = 0; j < 8; j++)
        if (base + j < N) off[base + j] = excl + c[j];
    if (t == 1023) off[N] = sums[1023];
}

__global__ __launch_bounds__(256) void kScatter(const int* __restrict__ pe,
    const int* __restrict__ off, int* __restrict__ pos, int* __restrict__ perm, int E){
    int e = blockIdx.x * 256 + threadIdx.x;
    if (e < E){
        int i = pe[(size_t)e*2];
        int slot = atomicAdd(&pos[i], 1);
        perm[off[i] + slot] = e;
    }
}

// ---------------- Kernel B1: batched fused edge MLP, MFMA layer-2 ----------------
// Block = 64 edges (2 batches of 32) from CSR-sorted perm.
// Layer1: thread t = col j; x -> swizzled bf16 LDS tile [32e][256k].
// Layer2: 16x16x32 bf16 MFMA; W2t fragments in registers (whole block lifetime).
__global__ __launch_bounds__(256) void kB1(
    const int* __restrict__ pe,
    const float* __restrict__ EPI, const float* __restrict__ RCW,
    const float* __restrict__ U, const float* __restrict__ T,
    const float* __restrict__ msg_w1,
    const unsigned short* __restrict__ w2t, const float* __restrict__ msg_b2,
    const float* __restrict__ msg_w3, const float* __restrict__ msg_b3,
    const int* __restrict__ perm,
    float* __restrict__ rho, int E)
{
    __shared__ unsigned short x_lds[32 * 256];   // 16 KB, XOR-swizzled
    __shared__ int   eidx_l[32];
    __shared__ int   ai_l[32];
    __shared__ int   pp_l[32];
    __shared__ float4 rc4_l[32];
    __shared__ float part[4][32];

    char* xbase = (char*)x_lds;

    const int t  = threadIdx.x;
    const int l  = t & 63;
    const int w  = t >> 6;         // wave 0..3
    const int lq = l >> 4;         // 0..3
    const int lm = l & 15;

    // layer-1 weights (col t of W1a) in registers
    float w1a[DRBF];
    #pragma unroll
    for (int k = 0; k < DRBF; k++) w1a[k] = msg_w1[(size_t)k * F_DIM + t];

    // B fragments: wave w owns h = w*32 .. w*32+31 (2 n-tiles of 16)
    bf16x8 bfr[2][8];
    #pragma unroll
    for (int nt2 = 0; nt2 < 2; nt2++){
        const int h = w*32 + nt2*16 + lm;
        #pragma unroll
        for (int kb = 0; kb < 8; kb++)
            bfr[nt2][kb] = *(const bf16x8*)(w2t + (size_t)h * F_DIM + kb*32 + lq*8);
    }
    const float b2v0 = msg_b2[w*32 + lm];
    const float b2v1 = msg_b2[w*32 + 16 + lm];
    const float w3v0 = msg_w3[w*32 + lm];
    const float w3v1 = msg_w3[w*32 + 16 + lm];
    const float b3   = msg_b3[0];

    const int e0 = blockIdx.x * 64;

    for (int bb = 0; bb < 2; bb++){
        const int e0b = e0 + bb * 32;

        if (t < 32){
            int s = min(e0b + t, E - 1);
            int ee = perm[s];
            eidx_l[t] = ee;
            ai_l[t]   = pe[(size_t)ee*2];
            pp_l[t]   = pe[(size_t)ee*2 + 1];
            rc4_l[t]  = *(const float4*)&RCW[(size_t)ee*4];
        }
        __syncthreads();

        // ---- layer 1: x[e][t] ----
        #pragma unroll 2
        for (int e = 0; e < 32; e++){
            const int i   = ai_l[e];
            const int eec = __builtin_amdgcn_readfirstlane(eidx_l[e]);
            const float4 rc = rc4_l[e];
            float acc = T[(size_t)i * F_DIM + t];
            const float* Up = U + (size_t)i * (3*F_DIM);
            float u0 = Up[t], u1 = Up[F_DIM + t], u2 = Up[2*F_DIM + t];
            const float* ep = EPI + (size_t)eec * DRBF;   // uniform -> s_loads
            float p0=0.f, p1=0.f, p2=0.f, p3=0.f;
            #pragma unroll
            for (int k = 0; k < DRBF; k += 4){
                p0 = fmaf(ep[k+0], w1a[k+0], p0);
                p1 = fmaf(ep[k+1], w1a[k+1], p1);
                p2 = fmaf(ep[k+2], w1a[k+2], p2);
                p3 = fmaf(ep[k+3], w1a[k+3], p3);
            }
            acc += (p0 + p1) + (p2 + p3);
            acc = fmaf(rc.x, u0, fmaf(rc.y, u1, fmaf(rc.z, u2, acc)));
            const int wofs = e*512 + ((t*2) ^ ((e & 7) << 4));
            *(unsigned short*)(xbase + wofs) = f2bf(silu_f(acc));
        }
        __syncthreads();

        // ---- layer 2: MFMA, C[32e][128h] = X @ W2 ----
        f32x4v acc00 = {0.f,0.f,0.f,0.f}, acc01 = {0.f,0.f,0.f,0.f};
        f32x4v acc10 = {0.f,0.f,0.f,0.f}, acc11 = {0.f,0.f,0.f,0.f};
        const int eA0 = lm;        // m-tile 0 row
        const int eA1 = 16 + lm;   // m-tile 1 row
        #pragma unroll
        for (int kb = 0; kb < 8; kb++){
            const int ko = kb*64 + lq*16;
            bf16x8 af0 = *(const bf16x8*)(xbase + eA0*512 + (ko ^ ((eA0 & 7) << 4)));
            bf16x8 af1 = *(const bf16x8*)(xbase + eA1*512 + (ko ^ ((eA1 & 7) << 4)));
            acc00 = __builtin_amdgcn_mfma_f32_16x16x32_bf16(af0, bfr[0][kb], acc00, 0, 0, 0);
            acc01 = __builtin_amdgcn_mfma_f32_16x16x32_bf16(af0, bfr[1][kb], acc01, 0, 0, 0);
            acc10 = __builtin_amdgcn_mfma_f32_16x16x32_bf16(af1, bfr[0][kb], acc10, 0, 0, 0);
            acc11 = __builtin_amdgcn_mfma_f32_16x16x32_bf16(af1, bfr[1][kb], acc11, 0, 0, 0);
        }

        // ---- layer 3: silu, *w3, reduce over h ----
        float pr0[4], pr1[4];
        #pragma unroll
        for (int r = 0; r < 4; r++){
            pr0[r] = silu_f(acc00[r] + b2v0) * w3v0 + silu_f(acc01[r] + b2v1) * w3v1;
            pr1[r] = silu_f(acc10[r] + b2v0) * w3v0 + silu_f(acc11[r] + b2v1) * w3v1;
        }
        #pragma unroll
        for (int r = 0; r < 4; r++){
            #pragma unroll
            for (int m = 8; m >= 1; m >>= 1){
                pr0[r] += __shfl_xor(pr0[r], m, 64);
                pr1[r] += __shfl_xor(pr1[r], m, 64);
            }
        }
        if (lm == 0){
            #pragma unroll
            for (int r = 0; r < 4; r++){
                part[w][lq*4 + r]      = pr0[r];
                part[w][16 + lq*4 + r] = pr1[r];
            }
        }
        __syncthreads();

        if (t < 32 && (e0b + t) < E){
            float tot = part[0][t] + part[1][t] + part[2][t] + part[3][t] + b3;
            atomicAdd(&rho[pp_l[t]], tot * rc4_l[t].w);
        }
        __syncthreads();
    }
}

extern "C" void kernel_launch(void* const* d_in, const int* in_sizes, int n_in,
                              void* d_out, int out_size, void* d_ws, size_t ws_size,
                              hipStream_t stream)
{
    const float* s_stack   = (const float*)d_in[0];
    const float* v_stack   = (const float*)d_in[1];
    const float* atom_xyz  = (const float*)d_in[2];
    const float* probe_xyz = (const float*)d_in[3];
    const float* cell      = (const float*)d_in[4];
    const float* disp      = (const float*)d_in[5];
    const float* attn_w1   = (const float*)d_in[6];
    const float* attn_b1   = (const float*)d_in[7];
    const float* attn_w2   = (const float*)d_in[8];
    const float* msg_w1    = (const float*)d_in[10];
    const float* msg_b1    = (const float*)d_in[11];
    const float* msg_w2    = (const float*)d_in[12];
    const float* msg_b2    = (const float*)d_in[13];
    const float* msg_w3    = (const float*)d_in[14];
    const float* msg_b3    = (const float*)d_in[15];
    const int*   pe        = (const int*)d_in[16];

    const int N = in_sizes[0] / (L_DIM * F_DIM);
    const int E = in_sizes[16] / 2;
    const int P = out_size;
    const size_t NF = (size_t)N * F_DIM;

    float* ws = (float*)d_ws;
    // region 1 [0,5NF): VJK|SJK|NI during phase A; then EPI|RCW|CSR during phase B
    float* VJK = ws;
    float* SJK = ws + 3*NF;
    float* NI  = ws + 4*NF;
    float* EPI = ws;
    float* RCW = ws + (size_t)E * DRBF;
    int*   cnt  = (int*)(ws + (size_t)E * 36);
    int*   pos  = cnt + N;
    int*   offs = pos + N;
    int*   perm = offs + N + 1;
    // W2t bf16 (64KB) in the tail of region 1 (dead after kA2 consumes NI)
    unsigned short* w2t = (unsigned short*)(ws + 5*NF - 16384);
    // region 2: U | T
    float* Ubuf = ws + 5*NF;
    float* Tbuf = ws + 8*NF;

    hipMemsetAsync(d_out, 0, (size_t)P * sizeof(float), stream);

    const int gA = (N + 7) / 8;
    kA1<<<gA, 256, 0, stream>>>(s_stack, v_stack, attn_w1, attn_b1, attn_w2,
                                VJK, SJK, NI, N);
    kA2<<<gA, 256, 0, stream>>>(msg_w1, msg_b1, VJK, SJK, NI, Ubuf, Tbuf, N);

    // region 1 now dead; reuse
    kPrep<<<FH_DIM, 256, 0, stream>>>(msg_w2, w2t);
    hipMemsetAsync(cnt, 0, 2 * (size_t)N * sizeof(int), stream);

    const int gE = (E + 255) / 256;
    kB0<<<gE, 256, 0, stream>>>(pe, disp, cell, atom_xyz, probe_xyz, EPI, RCW, E);
    kHist<<<gE, 256, 0, stream>>>(pe, cnt, E);
    kScan<<<1, 1024, 0, stream>>>(cnt, offs, N);
    kScatter<<<gE, 256, 0, stream>>>(pe, offs, pos, perm, E);

    kB1<<<(E + 63) / 64, 256, 0, stream>>>(pe, EPI, RCW, Ubuf, Tbuf, msg_w1,
                                           w2t, msg_b2, msg_w3, msg_b3,
                                           perm, (float*)d_out, E);
}

// Round 4
// 295.898 us; speedup vs baseline: 2.7579x; 1.7645x over previous
//
#include <hip/hip_runtime.h>
#include <math.h>
#include <stdint.h>

// PaiNN QM encoder, round 4.
//   U = V_JK @ W1b  (N,3,256)   T = b1 + n_i@W1c + S_JK@W1d  (N,256)
//   per edge: x = silu(T[i] + e_pi@W1a + r_hat.U[i]); m = (silu(x@W2+b2))@w3+b3
// Phase A: kA1a (attn weights), kA1b (streaming weighted sums -> bf16),
//          kA2u/kA2t (MFMA GEMMs with register-resident B fragments).
// Phase B: kB0 geometry, CSR binning, kB1 (MFMA layer-2) -- validated in r3.

#define L_DIM 6
#define F_DIM 256
#define FH_DIM 128
#define DRBF 32
#define CUTOFF_F 4.0f
#define PI_F 3.14159265358979323846f

using bf16x8 = __attribute__((ext_vector_type(8))) short;
using f32x4v = __attribute__((ext_vector_type(4))) float;

__device__ __forceinline__ float silu_f(float x){ return x / (1.f + __expf(-x)); }

__device__ __forceinline__ unsigned short f2bf(float f){
    uint32_t u = __float_as_uint(f);
    uint32_t r = (u + 0x7fffu + ((u >> 16) & 1u)) >> 16;   // RNE
    return (unsigned short)r;
}

// ---------------- kA1a: attention logits + softmax -> AW (N,6) ----------------
// Block = 8 atoms. s-tile staged in LDS (48 KB). Thread: atom a=t>>5, cols jg*4..+4.
__global__ __launch_bounds__(256) void kA1a(
    const float* __restrict__ s_stack,
    const float* __restrict__ attn_w1, const float* __restrict__ attn_b1,
    const float* __restrict__ attn_w2,
    float* __restrict__ AW, int N)
{
    __shared__ float s_l[8 * L_DIM * F_DIM];   // 48 KB
    __shared__ float llds[8][L_DIM];

    const int t  = threadIdx.x;
    const int n0 = blockIdx.x * 8;

    // stage 8 atoms' s rows (12288 floats), coalesced float4
    const float* src = s_stack + (size_t)n0 * (L_DIM * F_DIM);
    #pragma unroll
    for (int i = 0; i < 12; i++){
        float4 v = *(const float4*)(src + (size_t)(i * 256 + t) * 4);
        *(float4*)&s_l[(i * 256 + t) * 4] = v;
    }
    __syncthreads();

    const int a  = t >> 5;
    const int jg = t & 31;
    const float* sa = s_l + a * (L_DIM * F_DIM);

    float acc[L_DIM][4];
    #pragma unroll
    for (int l = 0; l < L_DIM; l++)
        #pragma unroll
        for (int jj = 0; jj < 4; jj++) acc[l][jj] = 0.f;

    #pragma unroll 2
    for (int f0 = 0; f0 < F_DIM; f0 += 4){
        float4 w0 = *(const float4*)&attn_w1[(size_t)(f0+0) * FH_DIM + jg*4];
        float4 w1 = *(const float4*)&attn_w1[(size_t)(f0+1) * FH_DIM + jg*4];
        float4 w2 = *(const float4*)&attn_w1[(size_t)(f0+2) * FH_DIM + jg*4];
        float4 w3 = *(const float4*)&attn_w1[(size_t)(f0+3) * FH_DIM + jg*4];
        float wv[4][4] = {{w0.x,w0.y,w0.z,w0.w},{w1.x,w1.y,w1.z,w1.w},
                          {w2.x,w2.y,w2.z,w2.w},{w3.x,w3.y,w3.z,w3.w}};
        #pragma unroll
        for (int l = 0; l < L_DIM; l++){
            float4 sv = *(const float4*)&sa[l * F_DIM + f0];
            float sa4[4] = {sv.x, sv.y, sv.z, sv.w};
            #pragma unroll
            for (int i = 0; i < 4; i++)
                #pragma unroll
                for (int jj = 0; jj < 4; jj++)
                    acc[l][jj] = fmaf(sa4[i], wv[i][jj], acc[l][jj]);
        }
    }

    float4 b1v = *(const float4*)&attn_b1[jg*4];
    float4 w2v = *(const float4*)&attn_w2[jg*4];
    float b1a[4] = {b1v.x, b1v.y, b1v.z, b1v.w};
    float w2a[4] = {w2v.x, w2v.y, w2v.z, w2v.w};

    #pragma unroll
    for (int l = 0; l < L_DIM; l++){
        float s = 0.f;
        #pragma unroll
        for (int jj = 0; jj < 4; jj++)
            s = fmaf(silu_f(acc[l][jj] + b1a[jj]), w2a[jj], s);
        #pragma unroll
        for (int m = 16; m >= 1; m >>= 1) s += __shfl_xor(s, m, 64);
        if (jg == 0) llds[a][l] = s;    // attn_b2 dropped: softmax-invariant
    }
    __syncthreads();
    if (t < 8){
        int n = min(n0 + t, N - 1);
        float mx = -1e30f;
        #pragma unroll
        for (int l = 0; l < L_DIM; l++) mx = fmaxf(mx, llds[t][l]);
        float e[L_DIM]; float s = 0.f;
        #pragma unroll
        for (int l = 0; l < L_DIM; l++){ e[l] = __expf(llds[t][l] - mx); s += e[l]; }
        float inv = 1.f / s;
        #pragma unroll
        for (int l = 0; l < L_DIM; l++) AW[(size_t)n * L_DIM + l] = e[l] * inv;
    }
}

// ---------------- kA1b: weighted sums -> VJKb (3N,256) bf16, NISb (N,512) bf16 ----------------
// One block per atom; thread t = feature. 24 independent coalesced loads.
__global__ __launch_bounds__(256) void kA1b(
    const float* __restrict__ s_stack, const float* __restrict__ v_stack,
    const float* __restrict__ AW,
    unsigned short* __restrict__ VJKb, unsigned short* __restrict__ NISb, int N)
{
    const int n = blockIdx.x;
    const int t = threadIdx.x;

    float aw[L_DIM];
    #pragma unroll
    for (int l = 0; l < L_DIM; l++) aw[l] = AW[(size_t)n * L_DIM + l];

    const float* sp = s_stack + (size_t)n * (L_DIM * F_DIM) + t;
    float sjk = 0.f;
    #pragma unroll
    for (int l = 0; l < L_DIM; l++) sjk = fmaf(aw[l], sp[l * F_DIM], sjk);

    const float* vp = v_stack + (size_t)n * (L_DIM * 3 * F_DIM) + t;
    float v0 = 0.f, v1 = 0.f, v2 = 0.f;
    #pragma unroll
    for (int l = 0; l < L_DIM; l++){
        v0 = fmaf(aw[l], vp[(l*3+0)*F_DIM], v0);
        v1 = fmaf(aw[l], vp[(l*3+1)*F_DIM], v1);
        v2 = fmaf(aw[l], vp[(l*3+2)*F_DIM], v2);
    }
    float ni = sqrtf(v0*v0 + v1*v1 + v2*v2);

    VJKb[((size_t)n*3 + 0) * F_DIM + t] = f2bf(v0);
    VJKb[((size_t)n*3 + 1) * F_DIM + t] = f2bf(v1);
    VJKb[((size_t)n*3 + 2) * F_DIM + t] = f2bf(v2);
    NISb[(size_t)n * 512 + t]        = f2bf(ni);
    NISb[(size_t)n * 512 + 256 + t]  = f2bf(sjk);
}

// ---------------- kPrep: transpose/convert weights to bf16 ----------------
// w1bt[j][k]=W1b[k][j] (256x256); w1cdt[j][k]=W1cd[k][j] (256x512); w2t[h][k]=W2[k][h]
__global__ __launch_bounds__(256) void kPrep(
    const float* __restrict__ msg_w1, const float* __restrict__ msg_w2,
    unsigned short* __restrict__ w1bt, unsigned short* __restrict__ w1cdt,
    unsigned short* __restrict__ w2t)
{
    int idx = blockIdx.x * 256 + threadIdx.x;
    if (idx < 65536){
        int k = idx >> 8, j = idx & 255;
        w1bt[(size_t)j * 256 + k] = f2bf(msg_w1[(size_t)(DRBF + k) * F_DIM + j]);
    } else if (idx < 65536 + 131072){
        int i2 = idx - 65536;
        int k = i2 >> 8, j = i2 & 255;        // k in [0,512): rows DRBF+256+k
        w1cdt[(size_t)j * 512 + k] = f2bf(msg_w1[(size_t)(DRBF + 256 + k) * F_DIM + j]);
    } else {
        int i3 = idx - 65536 - 131072;        // [0,32768)
        int k = i3 >> 7, h = i3 & 127;
        w2t[(size_t)h * 256 + k] = f2bf(msg_w2[(size_t)k * FH_DIM + h]);
    }
}

// ---------------- kA2u: U = VJKb @ W1b (MFMA) ----------------
// Block: 128 rows x 256 cols. Wave w owns cols w*64..+64 (4 col-tiles), B frags in regs.
__global__ __launch_bounds__(256) void kA2u(
    const unsigned short* __restrict__ VJKb, const unsigned short* __restrict__ w1bt,
    float* __restrict__ U, int M)
{
    const int t  = threadIdx.x;
    const int l  = t & 63;
    const int w  = t >> 6;
    const int lm = l & 15, lq = l >> 4;

    bf16x8 bfr[4][8];
    #pragma unroll
    for (int ct = 0; ct < 4; ct++)
        #pragma unroll
        for (int kb = 0; kb < 8; kb++)
            bfr[ct][kb] = *(const bf16x8*)(w1bt + (size_t)(w*64 + ct*16 + lm) * 256 + kb*32 + lq*8);

    const int r00 = blockIdx.x * 128;
    #pragma unroll 1
    for (int mt = 0; mt < 8; mt++){
        const int r0 = r00 + mt * 16;
        bf16x8 af[8];
        #pragma unroll
        for (int kb = 0; kb < 8; kb++)
            af[kb] = *(const bf16x8*)(VJKb + (size_t)(r0 + lm) * 256 + kb*32 + lq*8);
        f32x4v acc[4];
        #pragma unroll
        for (int ct = 0; ct < 4; ct++) acc[ct] = (f32x4v){0.f,0.f,0.f,0.f};
        #pragma unroll
        for (int kb = 0; kb < 8; kb++)
            #pragma unroll
            for (int ct = 0; ct < 4; ct++)
                acc[ct] = __builtin_amdgcn_mfma_f32_16x16x32_bf16(af[kb], bfr[ct][kb], acc[ct], 0, 0, 0);
        #pragma unroll
        for (int ct = 0; ct < 4; ct++){
            const int col = w*64 + ct*16 + lm;
            #pragma unroll
            for (int r = 0; r < 4; r++)
                U[(size_t)(r0 + lq*4 + r) * 256 + col] = acc[ct][r];
        }
    }
}

// ---------------- kA2t: T = b1 + NISb @ W1cd (MFMA, K=512) ----------------
// Block: 128 rows x 128 cols (half ch). Wave w owns 2 col-tiles.
__global__ __launch_bounds__(256) void kA2t(
    const unsigned short* __restrict__ NISb, const unsigned short* __restrict__ w1cdt,
    const float* __restrict__ msg_b1,
    float* __restrict__ T, int M)
{
    const int t  = threadIdx.x;
    const int l  = t & 63;
    const int w  = t >> 6;
    const int lm = l & 15, lq = l >> 4;

    const int ch = blockIdx.x & 1;
    const int bm = blockIdx.x >> 1;

    bf16x8 bfr[2][16];
    #pragma unroll
    for (int ct = 0; ct < 2; ct++)
        #pragma unroll
        for (int kb = 0; kb < 16; kb++)
            bfr[ct][kb] = *(const bf16x8*)(w1cdt + (size_t)(ch*128 + w*32 + ct*16 + lm) * 512 + kb*32 + lq*8);

    const int r00 = bm * 128;
    #pragma unroll 1
    for (int mt = 0; mt < 8; mt++){
        const int r0 = r00 + mt * 16;
        bf16x8 af[16];
        #pragma unroll
        for (int kb = 0; kb < 16; kb++)
            af[kb] = *(const bf16x8*)(NISb + (size_t)(r0 + lm) * 512 + kb*32 + lq*8);
        f32x4v acc[2];
        #pragma unroll
        for (int ct = 0; ct < 2; ct++) acc[ct] = (f32x4v){0.f,0.f,0.f,0.f};
        #pragma unroll
        for (int kb = 0; kb < 16; kb++)
            #pragma unroll
            for (int ct = 0; ct < 2; ct++)
                acc[ct] = __builtin_amdgcn_mfma_f32_16x16x32_bf16(af[kb], bfr[ct][kb], acc[ct], 0, 0, 0);
        #pragma unroll
        for (int ct = 0; ct < 2; ct++){
            const int col = ch*128 + w*32 + ct*16 + lm;
            const float bias = msg_b1[col];
            #pragma unroll
            for (int r = 0; r < 4; r++)
                T[(size_t)(r0 + lq*4 + r) * 256 + col] = acc[ct][r] + bias;
        }
    }
}

// ---------------- Kernel B0: per-edge geometry -> EPI (E,32), RCW (E,4) ----------------
__global__ __launch_bounds__(256) void kB0(
    const int* __restrict__ pe, const float* __restrict__ disp,
    const float* __restrict__ cell,
    const float* __restrict__ atom_xyz, const float* __restrict__ probe_xyz,
    float* __restrict__ EPI, float* __restrict__ RCW, int E)
{
    __shared__ float sl[DRBF][257];

    const int t = threadIdx.x;
    const int e0 = blockIdx.x * 256;
    const int e  = min(e0 + t, E - 1);

    int i = pe[(size_t)e*2];
    int p = pe[(size_t)e*2 + 1];
    float d0 = disp[(size_t)e*3], d1 = disp[(size_t)e*3+1], d2 = disp[(size_t)e*3+2];
    float sx = d0*cell[0] + d1*cell[3] + d2*cell[6];
    float sy = d0*cell[1] + d1*cell[4] + d2*cell[7];
    float sz = d0*cell[2] + d1*cell[5] + d2*cell[8];
    float dx = probe_xyz[(size_t)p*3+0] - (atom_xyz[(size_t)i*3+0] + sx);
    float dy = probe_xyz[(size_t)p*3+1] - (atom_xyz[(size_t)i*3+1] + sy);
    float dz = probe_xyz[(size_t)p*3+2] - (atom_xyz[(size_t)i*3+2] + sz);
    float dist = sqrtf(dx*dx + dy*dy + dz*dz);
    float inv = 1.f / (dist + 1e-8f);
    if (e0 + t < E){
        float4 rc;
        rc.x = dx * inv; rc.y = dy * inv; rc.z = dz * inv;
        rc.w = (dist < CUTOFF_F) ? 0.5f * (__cosf(PI_F * dist / CUTOFF_F) + 1.f) : 0.f;
        *(float4*)&RCW[(size_t)(e0 + t)*4] = rc;
    }
    float base = dist * (PI_F / CUTOFF_F);
    #pragma unroll
    for (int k = 0; k < DRBF; k++)
        sl[k][t] = __sinf(base * (float)(k+1)) * inv;
    __syncthreads();
    #pragma unroll 4
    for (int chunk = 0; chunk < 32; chunk++){
        int flat = chunk * 256 + t;
        int r = flat >> 5, c = flat & 31;
        if (e0 + r < E)
            EPI[(size_t)(e0 + r) * DRBF + c] = sl[c][r];
    }
}

// ---------------- CSR binning ----------------
__global__ __launch_bounds__(256) void kHist(const int* __restrict__ pe, int* __restrict__ cnt, int E){
    int e = blockIdx.x * 256 + threadIdx.x;
    if (e < E) atomicAdd(&cnt[pe[(size_t)e*2]], 1);
}

__global__ __launch_bounds__(1024) void kScan(const int* __restrict__ cnt, int* __restrict__ off, int N){
    __shared__ int sums[1024];
    const int t = threadIdx.x;
    const int base = t * 8;
    int c[8]; int s = 0;
    #pragma unroll
    for (int j = 0; j < 8; j++){
        int v = (base + j < N) ? cnt[base + j] : 0;
        c[j] = s; s += v;
    }
    sums[t] = s;
    __syncthreads();
    for (int d = 1; d < 1024; d <<= 1){
        int v = (t >= d) ? sums[t - d] : 0;
        __syncthreads();
        sums[t] += v;
        __syncthreads();
    }
    int excl = (t == 0) ? 0 : sums[t - 1];
    #pragma unroll
    for (int j = 0; j < 8; j++)
        if (base + j < N) off[base + j] = excl + c[j];
    if (t == 1023) off[N] = sums[1023];
}

__global__ __launch_bounds__(256) void kScatter(const int* __restrict__ pe,
    const int* __restrict__ off, int* __restrict__ pos, int* __restrict__ perm, int E){
    int e = blockIdx.x * 256 + threadIdx.x;
    if (e < E){
        int i = pe[(size_t)e*2];
        int slot = atomicAdd(&pos[i], 1);
        perm[off[i] + slot] = e;
    }
}

// ---------------- Kernel B1: batched fused edge MLP, MFMA layer-2 (validated r3) ----------------
__global__ __launch_bounds__(256) void kB1(
    const int* __restrict__ pe,
    const float* __restrict__ EPI, const float* __restrict__ RCW,
    const float* __restrict__ U, const float* __restrict__ T,
    const float* __restrict__ msg_w1,
    const unsigned short* __restrict__ w2t, const float* __restrict__ msg_b2,
    const float* __restrict__ msg_w3, const float* __restrict__ msg_b3,
    const int* __restrict__ perm,
    float* __restrict__ rho, int E)
{
    __shared__ unsigned short x_lds[32 * 256];   // 16 KB, XOR-swizzled
    __shared__ int   eidx_l[32];
    __shared__ int   ai_l[32];
    __shared__ int   pp_l[32];
    __shared__ float4 rc4_l[32];
    __shared__ float part[4][32];

    char* xbase = (char*)x_lds;

    const int t  = threadIdx.x;
    const int l  = t & 63;
    const int w  = t >> 6;
    const int lq = l >> 4;
    const int lm = l & 15;

    float w1a[DRBF];
    #pragma unroll
    for (int k = 0; k < DRBF; k++) w1a[k] = msg_w1[(size_t)k * F_DIM + t];

    bf16x8 bfr[2][8];
    #pragma unroll
    for (int nt2 = 0; nt2 < 2; nt2++){
        const int h = w*32 + nt2*16 + lm;
        #pragma unroll
        for (int kb = 0; kb < 8; kb++)
            bfr[nt2][kb] = *(const bf16x8*)(w2t + (size_t)h * F_DIM + kb*32 + lq*8);
    }
    const float b2v0 = msg_b2[w*32 + lm];
    const float b2v1 = msg_b2[w*32 + 16 + lm];
    const float w3v0 = msg_w3[w*32 + lm];
    const float w3v1 = msg_w3[w*32 + 16 + lm];
    const float b3   = msg_b3[0];

    const int e0 = blockIdx.x * 64;

    for (int bb = 0; bb < 2; bb++){
        const int e0b = e0 + bb * 32;

        if (t < 32){
            int s = min(e0b + t, E - 1);
            int ee = perm[s];
            eidx_l[t] = ee;
            ai_l[t]   = pe[(size_t)ee*2];
            pp_l[t]   = pe[(size_t)ee*2 + 1];
            rc4_l[t]  = *(const float4*)&RCW[(size_t)ee*4];
        }
        __syncthreads();

        #pragma unroll 2
        for (int e = 0; e < 32; e++){
            const int i   = ai_l[e];
            const int eec = __builtin_amdgcn_readfirstlane(eidx_l[e]);
            const float4 rc = rc4_l[e];
            float acc = T[(size_t)i * F_DIM + t];
            const float* Up = U + (size_t)i * (3*F_DIM);
            float u0 = Up[t], u1 = Up[F_DIM + t], u2 = Up[2*F_DIM + t];
            const float* ep = EPI + (size_t)eec * DRBF;
            float p0=0.f, p1=0.f, p2=0.f, p3=0.f;
            #pragma unroll
            for (int k = 0; k < DRBF; k += 4){
                p0 = fmaf(ep[k+0], w1a[k+0], p0);
                p1 = fmaf(ep[k+1], w1a[k+1], p1);
                p2 = fmaf(ep[k+2], w1a[k+2], p2);
                p3 = fmaf(ep[k+3], w1a[k+3], p3);
            }
            acc += (p0 + p1) + (p2 + p3);
            acc = fmaf(rc.x, u0, fmaf(rc.y, u1, fmaf(rc.z, u2, acc)));
            const int wofs = e*512 + ((t*2) ^ ((e & 7) << 4));
            *(unsigned short*)(xbase + wofs) = f2bf(silu_f(acc));
        }
        __syncthreads();

        f32x4v acc00 = {0.f,0.f,0.f,0.f}, acc01 = {0.f,0.f,0.f,0.f};
        f32x4v acc10 = {0.f,0.f,0.f,0.f}, acc11 = {0.f,0.f,0.f,0.f};
        const int eA0 = lm;
        const int eA1 = 16 + lm;
        #pragma unroll
        for (int kb = 0; kb < 8; kb++){
            const int ko = kb*64 + lq*16;
            bf16x8 af0 = *(const bf16x8*)(xbase + eA0*512 + (ko ^ ((eA0 & 7) << 4)));
            bf16x8 af1 = *(const bf16x8*)(xbase + eA1*512 + (ko ^ ((eA1 & 7) << 4)));
            acc00 = __builtin_amdgcn_mfma_f32_16x16x32_bf16(af0, bfr[0][kb], acc00, 0, 0, 0);
            acc01 = __builtin_amdgcn_mfma_f32_16x16x32_bf16(af0, bfr[1][kb], acc01, 0, 0, 0);
            acc10 = __builtin_amdgcn_mfma_f32_16x16x32_bf16(af1, bfr[0][kb], acc10, 0, 0, 0);
            acc11 = __builtin_amdgcn_mfma_f32_16x16x32_bf16(af1, bfr[1][kb], acc11, 0, 0, 0);
        }

        float pr0[4], pr1[4];
        #pragma unroll
        for (int r = 0; r < 4; r++){
            pr0[r] = silu_f(acc00[r] + b2v0) * w3v0 + silu_f(acc01[r] + b2v1) * w3v1;
            pr1[r] = silu_f(acc10[r] + b2v0) * w3v0 + silu_f(acc11[r] + b2v1) * w3v1;
        }
        #pragma unroll
        for (int r = 0; r < 4; r++){
            #pragma unroll
            for (int m = 8; m >= 1; m >>= 1){
                pr0[r] += __shfl_xor(pr0[r], m, 64);
                pr1[r] += __shfl_xor(pr1[r], m, 64);
            }
        }
        if (lm == 0){
            #pragma unroll
            for (int r = 0; r < 4; r++){
                part[w][lq*4 + r]      = pr0[r];
                part[w][16 + lq*4 + r] = pr1[r];
            }
        }
        __syncthreads();

        if (t < 32 && (e0b + t) < E){
            float tot = part[0][t] + part[1][t] + part[2][t] + part[3][t] + b3;
            atomicAdd(&rho[pp_l[t]], tot * rc4_l[t].w);
        }
        __syncthreads();
    }
}

extern "C" void kernel_launch(void* const* d_in, const int* in_sizes, int n_in,
                              void* d_out, int out_size, void* d_ws, size_t ws_size,
                              hipStream_t stream)
{
    const float* s_stack   = (const float*)d_in[0];
    const float* v_stack   = (const float*)d_in[1];
    const float* atom_xyz  = (const float*)d_in[2];
    const float* probe_xyz = (const float*)d_in[3];
    const float* cell      = (const float*)d_in[4];
    const float* disp      = (const float*)d_in[5];
    const float* attn_w1   = (const float*)d_in[6];
    const float* attn_b1   = (const float*)d_in[7];
    const float* attn_w2   = (const float*)d_in[8];
    const float* msg_w1    = (const float*)d_in[10];
    const float* msg_b1    = (const float*)d_in[11];
    const float* msg_w2    = (const float*)d_in[12];
    const float* msg_b2    = (const float*)d_in[13];
    const float* msg_w3    = (const float*)d_in[14];
    const float* msg_b3    = (const float*)d_in[15];
    const int*   pe        = (const int*)d_in[16];

    const int N = in_sizes[0] / (L_DIM * F_DIM);
    const int E = in_sizes[16] / 2;
    const int P = out_size;
    const size_t NF = (size_t)N * F_DIM;     // 2,097,152 for N=8192

    float* ws = (float*)d_ws;
    // phase A (dead before kB0): VJKb bf16 [0,1.5NF), NISb bf16 [1.5NF,2.5NF)
    unsigned short* VJKb = (unsigned short*)ws;             // 3N x 256 bf16
    unsigned short* NISb = VJKb + 3*NF;                     // N x 512 bf16
    // phase B overlay: EPI [0,2NF), RCW [2NF,2.25NF)
    float* EPI = ws;
    float* RCW = ws + 2*NF;
    // persistent small regions
    float* AW   = ws + 5*NF/2;                              // N*6 floats
    unsigned short* w1bt  = (unsigned short*)(ws + 5*NF/2 + 65536);   // 256x256
    unsigned short* w1cdt = w1bt + 65536;                   // 256x512
    unsigned short* w2t   = w1cdt + 131072;                 // 128x256
    int* cnt  = (int*)(w2t + 32768);
    int* pos  = cnt + N;
    int* offs = pos + N;
    int* perm = offs + N + 1;
    // outputs of phase A2
    float* Ubuf = ws + 3*NF;                                // 3N x 256
    float* Tbuf = ws + 6*NF;                                // N x 256

    hipMemsetAsync(d_out, 0, (size_t)P * sizeof(float), stream);
    hipMemsetAsync(cnt, 0, 2 * (size_t)N * sizeof(int), stream);

    kPrep<<<896, 256, 0, stream>>>(msg_w1, msg_w2, w1bt, w1cdt, w2t);

    kA1a<<<(N + 7) / 8, 256, 0, stream>>>(s_stack, attn_w1, attn_b1, attn_w2, AW, N);
    kA1b<<<N, 256, 0, stream>>>(s_stack, v_stack, AW, VJKb, NISb, N);

    kA2u<<<(3 * N) / 128, 256, 0, stream>>>(VJKb, w1bt, Ubuf, 3 * N);
    kA2t<<<(N / 128) * 2, 256, 0, stream>>>(NISb, w1cdt, msg_b1, Tbuf, N);

    const int gE = (E + 255) / 256;
    kB0<<<gE, 256, 0, stream>>>(pe, disp, cell, atom_xyz, probe_xyz, EPI, RCW, E);
    kHist<<<gE, 256, 0, stream>>>(pe, cnt, E);
    kScan<<<1, 1024, 0, stream>>>(cnt, offs, N);
    kScatter<<<gE, 256, 0, stream>>>(pe, offs, pos, perm, E);

    kB1<<<(E + 63) / 64, 256, 0, stream>>>(pe, EPI, RCW, Ubuf, Tbuf, msg_w1,
                                           w2t, msg_b2, msg_w3, msg_b3,
                                           perm, (float*)d_out, E);
}

// Round 5
// 213.062 us; speedup vs baseline: 3.8302x; 1.3888x over previous
//
#include <hip/hip_runtime.h>
#include <math.h>
#include <stdint.h>

// PaiNN QM encoder, round 5.
//   U = V_JK @ W1b  (N,3,256)   T = b1 + n_i@W1c + S_JK@W1d  (N,256)
//   per edge: x = silu(T[i] + e_pi@W1a + r_hat.U[i]); m = (silu(x@W2+b2))@w3+b3
// kA1: single-pass attention (logits GEMM from LDS, softmax, weighted sums).
// kA2u/kA2t: MFMA GEMMs (validated r4).
// kB1: geometry folded in (no kB0, no EPI buffer); RBF term via MFMA1;
//      per-(edge,col) epilogue in MFMA C-layout; MFMA2 layer-2 (validated r3/r4).

#define L_DIM 6
#define F_DIM 256
#define FH_DIM 128
#define DRBF 32
#define CUTOFF_F 4.0f
#define PI_F 3.14159265358979323846f

using bf16x8 = __attribute__((ext_vector_type(8))) short;
using f32x4v = __attribute__((ext_vector_type(4))) float;

__device__ __forceinline__ float silu_f(float x){ return x / (1.f + __expf(-x)); }

__device__ __forceinline__ unsigned short f2bf(float f){
    uint32_t u = __float_as_uint(f);
    uint32_t r = (u + 0x7fffu + ((u >> 16) & 1u)) >> 16;   // RNE
    return (unsigned short)r;
}

// ---------------- kA1: attention logits + softmax + weighted sums (one s pass) ----------------
// Block = 8 atoms. s staged in LDS once; logits GEMM from LDS; weighted sums
// re-use LDS s and stream v_stack. Outputs bf16 VJKb (3N,256), NISb (N,512).
__global__ __launch_bounds__(256) void kA1(
    const float* __restrict__ s_stack, const float* __restrict__ v_stack,
    const float* __restrict__ attn_w1, const float* __restrict__ attn_b1,
    const float* __restrict__ attn_w2,
    unsigned short* __restrict__ VJKb, unsigned short* __restrict__ NISb, int N)
{
    __shared__ float s_l[8 * L_DIM * F_DIM];   // 48 KB
    __shared__ float llds[8][L_DIM];

    const int t  = threadIdx.x;
    const int n0 = blockIdx.x * 8;

    // stage 8 atoms' s rows (12288 floats), coalesced float4
    const float* src = s_stack + (size_t)n0 * (L_DIM * F_DIM);
    #pragma unroll
    for (int i = 0; i < 12; i++){
        float4 v = *(const float4*)(src + (size_t)(i * 256 + t) * 4);
        *(float4*)&s_l[(i * 256 + t) * 4] = v;
    }
    __syncthreads();

    const int a  = t >> 5;
    const int jg = t & 31;
    const float* sa = s_l + a * (L_DIM * F_DIM);

    float acc[L_DIM][4];
    #pragma unroll
    for (int l = 0; l < L_DIM; l++)
        #pragma unroll
        for (int jj = 0; jj < 4; jj++) acc[l][jj] = 0.f;

    #pragma unroll 2
    for (int f0 = 0; f0 < F_DIM; f0 += 4){
        float4 w0 = *(const float4*)&attn_w1[(size_t)(f0+0) * FH_DIM + jg*4];
        float4 w1 = *(const float4*)&attn_w1[(size_t)(f0+1) * FH_DIM + jg*4];
        float4 w2 = *(const float4*)&attn_w1[(size_t)(f0+2) * FH_DIM + jg*4];
        float4 w3 = *(const float4*)&attn_w1[(size_t)(f0+3) * FH_DIM + jg*4];
        float wv[4][4] = {{w0.x,w0.y,w0.z,w0.w},{w1.x,w1.y,w1.z,w1.w},
                          {w2.x,w2.y,w2.z,w2.w},{w3.x,w3.y,w3.z,w3.w}};
        #pragma unroll
        for (int l = 0; l < L_DIM; l++){
            float4 sv = *(const float4*)&sa[l * F_DIM + f0];
            float sa4[4] = {sv.x, sv.y, sv.z, sv.w};
            #pragma unroll
            for (int i = 0; i < 4; i++)
                #pragma unroll
                for (int jj = 0; jj < 4; jj++)
                    acc[l][jj] = fmaf(sa4[i], wv[i][jj], acc[l][jj]);
        }
    }

    float4 b1v = *(const float4*)&attn_b1[jg*4];
    float4 w2v = *(const float4*)&attn_w2[jg*4];
    float b1a[4] = {b1v.x, b1v.y, b1v.z, b1v.w};
    float w2a[4] = {w2v.x, w2v.y, w2v.z, w2v.w};

    #pragma unroll
    for (int l = 0; l < L_DIM; l++){
        float s = 0.f;
        #pragma unroll
        for (int jj = 0; jj < 4; jj++)
            s = fmaf(silu_f(acc[l][jj] + b1a[jj]), w2a[jj], s);
        #pragma unroll
        for (int m = 16; m >= 1; m >>= 1) s += __shfl_xor(s, m, 64);
        if (jg == 0) llds[a][l] = s;    // attn_b2 dropped: softmax-invariant
    }
    __syncthreads();
    if (t < 8){
        float mx = -1e30f;
        #pragma unroll
        for (int l = 0; l < L_DIM; l++) mx = fmaxf(mx, llds[t][l]);
        float e[L_DIM]; float s = 0.f;
        #pragma unroll
        for (int l = 0; l < L_DIM; l++){ e[l] = __expf(llds[t][l] - mx); s += e[l]; }
        float inv = 1.f / s;
        #pragma unroll
        for (int l = 0; l < L_DIM; l++) llds[t][l] = e[l] * inv;
    }
    __syncthreads();

    // weighted sums: thread t = feature; s from LDS, v streamed
    for (int aa = 0; aa < 8; aa++){
        int nn = n0 + aa; if (nn >= N) break;
        float aw[L_DIM];
        #pragma unroll
        for (int l = 0; l < L_DIM; l++) aw[l] = llds[aa][l];

        const float* sp = s_l + aa * (L_DIM * F_DIM) + t;
        float sjk = 0.f;
        #pragma unroll
        for (int l = 0; l < L_DIM; l++) sjk = fmaf(aw[l], sp[l * F_DIM], sjk);

        const float* vp = v_stack + (size_t)nn * (L_DIM * 3 * F_DIM) + t;
        float v0 = 0.f, v1 = 0.f, v2 = 0.f;
        #pragma unroll
        for (int l = 0; l < L_DIM; l++){
            v0 = fmaf(aw[l], vp[(l*3+0)*F_DIM], v0);
            v1 = fmaf(aw[l], vp[(l*3+1)*F_DIM], v1);
            v2 = fmaf(aw[l], vp[(l*3+2)*F_DIM], v2);
        }
        float ni = sqrtf(v0*v0 + v1*v1 + v2*v2);

        VJKb[((size_t)nn*3 + 0) * F_DIM + t] = f2bf(v0);
        VJKb[((size_t)nn*3 + 1) * F_DIM + t] = f2bf(v1);
        VJKb[((size_t)nn*3 + 2) * F_DIM + t] = f2bf(v2);
        NISb[(size_t)nn * 512 + t]       = f2bf(ni);
        NISb[(size_t)nn * 512 + 256 + t] = f2bf(sjk);
    }
}

// ---------------- kPrep: transpose/convert weights to bf16 ----------------
__global__ __launch_bounds__(256) void kPrep(
    const float* __restrict__ msg_w1, const float* __restrict__ msg_w2,
    unsigned short* __restrict__ w1bt, unsigned short* __restrict__ w1cdt,
    unsigned short* __restrict__ w2t)
{
    int idx = blockIdx.x * 256 + threadIdx.x;
    if (idx < 65536){
        int k = idx >> 8, j = idx & 255;
        w1bt[(size_t)j * 256 + k] = f2bf(msg_w1[(size_t)(DRBF + k) * F_DIM + j]);
    } else if (idx < 65536 + 131072){
        int i2 = idx - 65536;
        int k = i2 >> 8, j = i2 & 255;
        w1cdt[(size_t)j * 512 + k] = f2bf(msg_w1[(size_t)(DRBF + 256 + k) * F_DIM + j]);
    } else {
        int i3 = idx - 65536 - 131072;
        int k = i3 >> 7, h = i3 & 127;
        w2t[(size_t)h * 256 + k] = f2bf(msg_w2[(size_t)k * FH_DIM + h]);
    }
}

// ---------------- kA2u: U = VJKb @ W1b (MFMA, validated r4) ----------------
__global__ __launch_bounds__(256) void kA2u(
    const unsigned short* __restrict__ VJKb, const unsigned short* __restrict__ w1bt,
    float* __restrict__ U, int M)
{
    const int t  = threadIdx.x;
    const int l  = t & 63;
    const int w  = t >> 6;
    const int lm = l & 15, lq = l >> 4;

    bf16x8 bfr[4][8];
    #pragma unroll
    for (int ct = 0; ct < 4; ct++)
        #pragma unroll
        for (int kb = 0; kb < 8; kb++)
            bfr[ct][kb] = *(const bf16x8*)(w1bt + (size_t)(w*64 + ct*16 + lm) * 256 + kb*32 + lq*8);

    const int r00 = blockIdx.x * 128;
    #pragma unroll 1
    for (int mt = 0; mt < 8; mt++){
        const int r0 = r00 + mt * 16;
        bf16x8 af[8];
        #pragma unroll
        for (int kb = 0; kb < 8; kb++)
            af[kb] = *(const bf16x8*)(VJKb + (size_t)(r0 + lm) * 256 + kb*32 + lq*8);
        f32x4v acc[4];
        #pragma unroll
        for (int ct = 0; ct < 4; ct++) acc[ct] = (f32x4v){0.f,0.f,0.f,0.f};
        #pragma unroll
        for (int kb = 0; kb < 8; kb++)
            #pragma unroll
            for (int ct = 0; ct < 4; ct++)
                acc[ct] = __builtin_amdgcn_mfma_f32_16x16x32_bf16(af[kb], bfr[ct][kb], acc[ct], 0, 0, 0);
        #pragma unroll
        for (int ct = 0; ct < 4; ct++){
            const int col = w*64 + ct*16 + lm;
            #pragma unroll
            for (int r = 0; r < 4; r++)
                U[(size_t)(r0 + lq*4 + r) * 256 + col] = acc[ct][r];
        }
    }
}

// ---------------- kA2t: T = b1 + NISb @ W1cd (MFMA, K=512, validated r4) ----------------
__global__ __launch_bounds__(256) void kA2t(
    const unsigned short* __restrict__ NISb, const unsigned short* __restrict__ w1cdt,
    const float* __restrict__ msg_b1,
    float* __restrict__ T, int M)
{
    const int t  = threadIdx.x;
    const int l  = t & 63;
    const int w  = t >> 6;
    const int lm = l & 15, lq = l >> 4;

    const int ch = blockIdx.x & 1;
    const int bm = blockIdx.x >> 1;

    bf16x8 bfr[2][16];
    #pragma unroll
    for (int ct = 0; ct < 2; ct++)
        #pragma unroll
        for (int kb = 0; kb < 16; kb++)
            bfr[ct][kb] = *(const bf16x8*)(w1cdt + (size_t)(ch*128 + w*32 + ct*16 + lm) * 512 + kb*32 + lq*8);

    const int r00 = bm * 128;
    #pragma unroll 1
    for (int mt = 0; mt < 8; mt++){
        const int r0 = r00 + mt * 16;
        bf16x8 af[16];
        #pragma unroll
        for (int kb = 0; kb < 16; kb++)
            af[kb] = *(const bf16x8*)(NISb + (size_t)(r0 + lm) * 512 + kb*32 + lq*8);
        f32x4v acc[2];
        #pragma unroll
        for (int ct = 0; ct < 2; ct++) acc[ct] = (f32x4v){0.f,0.f,0.f,0.f};
        #pragma unroll
        for (int kb = 0; kb < 16; kb++)
            #pragma unroll
            for (int ct = 0; ct < 2; ct++)
                acc[ct] = __builtin_amdgcn_mfma_f32_16x16x32_bf16(af[kb], bfr[ct][kb], acc[ct], 0, 0, 0);
        #pragma unroll
        for (int ct = 0; ct < 2; ct++){
            const int col = ch*128 + w*32 + ct*16 + lm;
            const float bias = msg_b1[col];
            #pragma unroll
            for (int r = 0; r < 4; r++)
                T[(size_t)(r0 + lq*4 + r) * 256 + col] = acc[ct][r] + bias;
        }
    }
}

// ---------------- CSR binning ----------------
__global__ __launch_bounds__(256) void kHist(const int* __restrict__ pe, int* __restrict__ cnt, int E){
    int e = blockIdx.x * 256 + threadIdx.x;
    if (e < E) atomicAdd(&cnt[pe[(size_t)e*2]], 1);
}

__global__ __launch_bounds__(1024) void kScan(const int* __restrict__ cnt, int* __restrict__ off, int N){
    __shared__ int sums[1024];
    const int t = threadIdx.x;
    const int base = t * 8;
    int c[8]; int s = 0;
    #pragma unroll
    for (int j = 0; j < 8; j++){
        int v = (base + j < N) ? cnt[base + j] : 0;
        c[j] = s; s += v;
    }
    sums[t] = s;
    __syncthreads();
    for (int d = 1; d < 1024; d <<= 1){
        int v = (t >= d) ? sums[t - d] : 0;
        __syncthreads();
        sums[t] += v;
        __syncthreads();
    }
    int excl = (t == 0) ? 0 : sums[t - 1];
    #pragma unroll
    for (int j = 0; j < 8; j++)
        if (base + j < N) off[base + j] = excl + c[j];
    if (t == 1023) off[N] = sums[1023];
}

__global__ __launch_bounds__(256) void kScatter(const int* __restrict__ pe,
    const int* __restrict__ off, int* __restrict__ pos, int* __restrict__ perm, int E){
    int e = blockIdx.x * 256 + threadIdx.x;
    if (e < E){
        int i = pe[(size_t)e*2];
        int slot = atomicAdd(&pos[i], 1);
        perm[off[i] + slot] = e;
    }
}

// ---------------- kB1: fused geometry + edge MLP + scatter ----------------
// Block = 128 edges (4 batches of 32) from CSR-sorted perm. Per batch:
//  stage: 8 threads/edge compute dist/r_hat/cw + 4 RBF sins -> epi_b bf16 LDS
//  MFMA1: p[32e][256c] = epi @ W1a (B-frags built once per block)
//  pairs: z = p + T[i][c] + r_hat.U[i][c] (coalesced, MFMA C-layout), silu -> x_lds
//  MFMA2: x @ W2 (validated r3/r4) + silu/w3 reduce + atomicAdd
__global__ __launch_bounds__(256) void kB1(
    const int* __restrict__ pe, const float* __restrict__ disp,
    const float* __restrict__ cell,
    const float* __restrict__ atom_xyz, const float* __restrict__ probe_xyz,
    const float* __restrict__ U, const float* __restrict__ T,
    const float* __restrict__ msg_w1,
    const unsigned short* __restrict__ w2t, const float* __restrict__ msg_b2,
    const float* __restrict__ msg_w3, const float* __restrict__ msg_b3,
    const int* __restrict__ perm,
    float* __restrict__ rho, int E)
{
    __shared__ unsigned short x_lds[32 * 256];   // 16 KB, XOR-swizzled
    __shared__ unsigned short epi_b[32 * 40];    // 2.5 KB, bf16 A-tile (pad 40)
    __shared__ int   ai_l[32];
    __shared__ int   pp_l[32];
    __shared__ float4 rc4_l[32];
    __shared__ float part[4][32];

    char* xbase = (char*)x_lds;

    const int t  = threadIdx.x;
    const int l  = t & 63;
    const int w  = t >> 6;
    const int lq = l >> 4;
    const int lm = l & 15;

    // cell in registers
    const float c0 = cell[0], c1 = cell[1], c2 = cell[2];
    const float c3 = cell[3], c4 = cell[4], c5 = cell[5];
    const float c6 = cell[6], c7 = cell[7], c8 = cell[8];

    // W1a B-fragments: lane holds W1a[k=lq*8+j][col=w*64+nt*16+lm]
    bf16x8 w1afr[4];
    #pragma unroll
    for (int nt = 0; nt < 4; nt++){
        const int col = w*64 + nt*16 + lm;
        bf16x8 v;
        #pragma unroll
        for (int j = 0; j < 8; j++)
            v[j] = (short)f2bf(msg_w1[(size_t)(lq*8 + j) * F_DIM + col]);
        w1afr[nt] = v;
    }

    // W2 B-fragments (validated r3/r4)
    bf16x8 bfr[2][8];
    #pragma unroll
    for (int nt2 = 0; nt2 < 2; nt2++){
        const int h = w*32 + nt2*16 + lm;
        #pragma unroll
        for (int kb = 0; kb < 8; kb++)
            bfr[nt2][kb] = *(const bf16x8*)(w2t + (size_t)h * F_DIM + kb*32 + lq*8);
    }
    const float b2v0 = msg_b2[w*32 + lm];
    const float b2v1 = msg_b2[w*32 + 16 + lm];
    const float w3v0 = msg_w3[w*32 + lm];
    const float w3v1 = msg_w3[w*32 + 16 + lm];
    const float b3   = msg_b3[0];

    const int e0 = blockIdx.x * 128;

    for (int bb = 0; bb < 4; bb++){
        const int e0b = e0 + bb * 32;

        // ---- stage: geometry + RBF (8 threads per edge) ----
        {
            const int slot = t >> 3, q = t & 7;
            const int s  = min(e0b + slot, E - 1);
            const int ee = perm[s];
            const int ia = pe[(size_t)ee*2];
            const int ip = pe[(size_t)ee*2 + 1];
            const float d0 = disp[(size_t)ee*3], d1 = disp[(size_t)ee*3+1], d2 = disp[(size_t)ee*3+2];
            const float sx = d0*c0 + d1*c3 + d2*c6;
            const float sy = d0*c1 + d1*c4 + d2*c7;
            const float sz = d0*c2 + d1*c5 + d2*c8;
            const float dx = probe_xyz[(size_t)ip*3+0] - (atom_xyz[(size_t)ia*3+0] + sx);
            const float dy = probe_xyz[(size_t)ip*3+1] - (atom_xyz[(size_t)ia*3+1] + sy);
            const float dz = probe_xyz[(size_t)ip*3+2] - (atom_xyz[(size_t)ia*3+2] + sz);
            const float dist = sqrtf(dx*dx + dy*dy + dz*dz);
            const float inv  = 1.f / (dist + 1e-8f);
            const float base = dist * (PI_F / CUTOFF_F);
            ushort4 eb;
            eb.x = f2bf(__sinf(base * (float)(q*4 + 1)) * inv);
            eb.y = f2bf(__sinf(base * (float)(q*4 + 2)) * inv);
            eb.z = f2bf(__sinf(base * (float)(q*4 + 3)) * inv);
            eb.w = f2bf(__sinf(base * (float)(q*4 + 4)) * inv);
            *(ushort4*)&epi_b[slot*40 + q*4] = eb;
            if (q == 0){
                ai_l[slot] = ia;
                pp_l[slot] = ip;
                float cw = (dist < CUTOFF_F) ? 0.5f * (__cosf(base) + 1.f) : 0.f;
                rc4_l[slot] = (float4){dx*inv, dy*inv, dz*inv, cw};
            }
        }
        __syncthreads();

        // ---- MFMA1: p = epi (32x32) @ W1a (32x256) ----
        f32x4v pacc[2][4];
        #pragma unroll
        for (int mt = 0; mt < 2; mt++)
            #pragma unroll
            for (int nt = 0; nt < 4; nt++) pacc[mt][nt] = (f32x4v){0.f,0.f,0.f,0.f};
        #pragma unroll
        for (int mt = 0; mt < 2; mt++){
            const bf16x8 af = *(const bf16x8*)&epi_b[(mt*16 + lm)*40 + lq*8];
            #pragma unroll
            for (int nt = 0; nt < 4; nt++)
                pacc[mt][nt] = __builtin_amdgcn_mfma_f32_16x16x32_bf16(af, w1afr[nt], pacc[mt][nt], 0, 0, 0);
        }

        // ---- pairs: z = p + T + r.U, silu -> x_lds (MFMA C-layout) ----
        #pragma unroll
        for (int mt = 0; mt < 2; mt++){
            #pragma unroll
            for (int r = 0; r < 4; r++){
                const int e = mt*16 + lq*4 + r;
                const int i = ai_l[e];
                const float4 rc = rc4_l[e];
                const float* Tp = T + (size_t)i * F_DIM;
                const float* Up = U + (size_t)i * (3*F_DIM);
                #pragma unroll
                for (int nt = 0; nt < 4; nt++){
                    const int col = w*64 + nt*16 + lm;
                    float z = pacc[mt][nt][r] + Tp[col];
                    z = fmaf(rc.x, Up[col],           z);
                    z = fmaf(rc.y, Up[F_DIM + col],   z);
                    z = fmaf(rc.z, Up[2*F_DIM + col], z);
                    const int wofs = e*512 + ((col*2) ^ ((e & 7) << 4));
                    *(unsigned short*)(xbase + wofs) = f2bf(silu_f(z));
                }
            }
        }
        __syncthreads();

        // ---- MFMA2: layer 2 + layer 3 (validated r3/r4) ----
        f32x4v acc00 = {0.f,0.f,0.f,0.f}, acc01 = {0.f,0.f,0.f,0.f};
        f32x4v acc10 = {0.f,0.f,0.f,0.f}, acc11 = {0.f,0.f,0.f,0.f};
        const int eA0 = lm;
        const int eA1 = 16 + lm;
        #pragma unroll
        for (int kb = 0; kb < 8; kb++){
            const int ko = kb*64 + lq*16;
            bf16x8 af0 = *(const bf16x8*)(xbase + eA0*512 + (ko ^ ((eA0 & 7) << 4)));
            bf16x8 af1 = *(const bf16x8*)(xbase + eA1*512 + (ko ^ ((eA1 & 7) << 4)));
            acc00 = __builtin_amdgcn_mfma_f32_16x16x32_bf16(af0, bfr[0][kb], acc00, 0, 0, 0);
            acc01 = __builtin_amdgcn_mfma_f32_16x16x32_bf16(af0, bfr[1][kb], acc01, 0, 0, 0);
            acc10 = __builtin_amdgcn_mfma_f32_16x16x32_bf16(af1, bfr[0][kb], acc10, 0, 0, 0);
            acc11 = __builtin_amdgcn_mfma_f32_16x16x32_bf16(af1, bfr[1][kb], acc11, 0, 0, 0);
        }

        float pr0[4], pr1[4];
        #pragma unroll
        for (int r = 0; r < 4; r++){
            pr0[r] = silu_f(acc00[r] + b2v0) * w3v0 + silu_f(acc01[r] + b2v1) * w3v1;
            pr1[r] = silu_f(acc10[r] + b2v0) * w3v0 + silu_f(acc11[r] + b2v1) * w3v1;
        }
        #pragma unroll
        for (int r = 0; r < 4; r++){
            #pragma unroll
            for (int m = 8; m >= 1; m >>= 1){
                pr0[r] += __shfl_xor(pr0[r], m, 64);
                pr1[r] += __shfl_xor(pr1[r], m, 64);
            }
        }
        if (lm == 0){
            #pragma unroll
            for (int r = 0; r < 4; r++){
                part[w][lq*4 + r]      = pr0[r];
                part[w][16 + lq*4 + r] = pr1[r];
            }
        }
        __syncthreads();

        if (t < 32 && (e0b + t) < E){
            float tot = part[0][t] + part[1][t] + part[2][t] + part[3][t] + b3;
            atomicAdd(&rho[pp_l[t]], tot * rc4_l[t].w);
        }
        __syncthreads();
    }
}

extern "C" void kernel_launch(void* const* d_in, const int* in_sizes, int n_in,
                              void* d_out, int out_size, void* d_ws, size_t ws_size,
                              hipStream_t stream)
{
    const float* s_stack   = (const float*)d_in[0];
    const float* v_stack   = (const float*)d_in[1];
    const float* atom_xyz  = (const float*)d_in[2];
    const float* probe_xyz = (const float*)d_in[3];
    const float* cell      = (const float*)d_in[4];
    const float* disp      = (const float*)d_in[5];
    const float* attn_w1   = (const float*)d_in[6];
    const float* attn_b1   = (const float*)d_in[7];
    const float* attn_w2   = (const float*)d_in[8];
    const float* msg_w1    = (const float*)d_in[10];
    const float* msg_b1    = (const float*)d_in[11];
    const float* msg_w2    = (const float*)d_in[12];
    const float* msg_b2    = (const float*)d_in[13];
    const float* msg_w3    = (const float*)d_in[14];
    const float* msg_b3    = (const float*)d_in[15];
    const int*   pe        = (const int*)d_in[16];

    const int N = in_sizes[0] / (L_DIM * F_DIM);
    const int E = in_sizes[16] / 2;
    const int P = out_size;
    const size_t NF = (size_t)N * F_DIM;

    float* ws = (float*)d_ws;
    unsigned short* VJKb = (unsigned short*)ws;          // 3N x 256 bf16  (1.5 NF floats)
    unsigned short* NISb = VJKb + 3*NF;                  // N x 512 bf16   (1.0 NF floats)
    float* Ubuf = ws + (5*NF)/2;                         // 3N x 256 f32
    float* Tbuf = Ubuf + 3*NF;                           // N x 256 f32
    unsigned short* w1bt  = (unsigned short*)(Tbuf + NF);  // 256x256 bf16
    unsigned short* w1cdt = w1bt + 65536;                  // 256x512 bf16
    unsigned short* w2t   = w1cdt + 131072;                // 128x256 bf16
    int* cnt  = (int*)(w2t + 32768);
    int* pos  = cnt + N;
    int* offs = pos + N;
    int* perm = offs + N + 1;

    hipMemsetAsync(d_out, 0, (size_t)P * sizeof(float), stream);
    hipMemsetAsync(cnt, 0, 2 * (size_t)N * sizeof(int), stream);

    kPrep<<<896, 256, 0, stream>>>(msg_w1, msg_w2, w1bt, w1cdt, w2t);

    kA1<<<(N + 7) / 8, 256, 0, stream>>>(s_stack, v_stack, attn_w1, attn_b1, attn_w2,
                                         VJKb, NISb, N);

    kA2u<<<(3 * N) / 128, 256, 0, stream>>>(VJKb, w1bt, Ubuf, 3 * N);
    kA2t<<<(N / 128) * 2, 256, 0, stream>>>(NISb, w1cdt, msg_b1, Tbuf, N);

    const int gE = (E + 255) / 256;
    kHist<<<gE, 256, 0, stream>>>(pe, cnt, E);
    kScan<<<1, 1024, 0, stream>>>(cnt, offs, N);
    kScatter<<<gE, 256, 0, stream>>>(pe, offs, pos, perm, E);

    kB1<<<(E + 127) / 128, 256, 0, stream>>>(pe, disp, cell, atom_xyz, probe_xyz,
                                             Ubuf, Tbuf, msg_w1,
                                             w2t, msg_b2, msg_w3, msg_b3,
                                             perm, (float*)d_out, E);
}